// Round 18
// baseline (434.478 us; speedup 1.0000x reference)
//
#include <hip/hip_runtime.h>
#include <cstdint>

// CrossViewBlockTransformer on MI355X (gfx950), round 18.
// LDS-pipe reduction round. Accounting showed the LDS pipe ~100% busy at the
// ~109us wall (stage+extract+RMW+sP+store-transpose ~380cy/block vs 255cy
// budget). Changes vs R16/R14:
//   1) FC operand swap: ao[kt] IS the A-frag of O^T, so
//      xaT[mt] = sum_kt MFMA(ao_bf16[kt], Wf4[mt][kt]) gives x with lane =
//      (channel 16mt+n, pixels 4g..4g+3) = dense 16B store quarters.
//      Output: registers -> global b128 (4 waves' quarters L1-merge into 64B
//      lines). RMW + store-transpose LDS traffic eliminated.
//   2) Residual read from the intact staging buffer (4x ds_read_b128).
//   3) gamma/beta in 8 registers (indexed by 16mt+n).
//   4) 4-wave WG, ZERO barriers (all LDS wave-private), R16 Xq staging,
//      R10 per-lane Xr (cross-wave L1 merge), counted vmcnt ledger.
// x matrix bit-identical to R14; GN lane-sum order differs -> absmax ~0.148.

typedef float  f4    __attribute__((ext_vector_type(4)));
typedef float  f32x4 __attribute__((ext_vector_type(4)));
typedef short  s16x4 __attribute__((ext_vector_type(4)));
typedef short  s16x8 __attribute__((ext_vector_type(8)));
typedef unsigned short u16;
typedef __bf16 bf16;

#define MFMA16(a,b,c) __builtin_amdgcn_mfma_f32_16x16x16bf16_1k((a),(b),(c),0,0,0)
#define MFMA32(a,b,c) __builtin_amdgcn_mfma_f32_16x16x32_bf16((a),(b),(c),0,0,0)

#define DPP_ROR(x, N)                                                         \
  __builtin_bit_cast(float, __builtin_amdgcn_mov_dpp(                         \
      __builtin_bit_cast(int, (x)), 0x120 + (N), 0xF, 0xF, 1))

// slot0=Wq(K32) slot1=Wk(K32) slot2=Wv(K32) slot3=Wfc(K16); 4 x 8KB
__device__ __align__(16) u16 g_wpack[4 * 4096];

__device__ __forceinline__ u16 bfbits(float x) {
  return __builtin_bit_cast(u16, (bf16)x);
}

__device__ __forceinline__ void gload_lds16(const float* g, float* l) {
  __builtin_amdgcn_global_load_lds(
      (const __attribute__((address_space(1))) void*)g,
      (__attribute__((address_space(3))) void*)l, 16, 0, 0);
}

// K32 frag: pack[t=a*2+b][l][j0..7] = W[16a + (l&15)][32b + 8*(l>>4) + j]
// K16 frag: pack[t=a*4+b][l][j0..3] = W[16a + (l&15)][16b + 4*(l>>4) + j]
__global__ void prep_w(const float* __restrict__ Wq, const float* __restrict__ Wk,
                       const float* __restrict__ Wv, const float* __restrict__ Wfc)
{
  const int t = blockIdx.x * 64 + threadIdx.x;   // 32 WGs x 64
  const float* Wm[3] = {Wq, Wk, Wv};
#pragma unroll
  for (int s = 0; s < 3; ++s) {
    const float* W = Wm[s];
    if (t < 512) {
      const int tile = t >> 6, l = t & 63;
      const int row = 16 * (tile >> 1) + (l & 15);
      const int col = 32 * (tile & 1) + 8 * (l >> 4);
#pragma unroll
      for (int j = 0; j < 8; ++j)
        g_wpack[s * 4096 + t * 8 + j] = bfbits(W[row * 64 + col + j]);
    }
  }
  if (t < 1024) {
    const int tile = t >> 6, l = t & 63;
    const int row = 16 * (tile >> 2) + (l & 15);
    const int col = 16 * (tile & 3) + 4 * (l >> 4);
#pragma unroll
    for (int j = 0; j < 4; ++j)
      g_wpack[3 * 4096 + t * 4 + j] = bfbits(Wfc[row * 64 + col + j]);
  }
}

__global__ void __launch_bounds__(256, 2)
cvbt18(const float* __restrict__ qx, const float* __restrict__ rx,
       const float* __restrict__ gw, const float* __restrict__ gb,
       float* __restrict__ out)
{
  // per-wave private Xq staging (ping-pong): chunk i (channels 16i..16i+15)
  // at [i*272]; X[c][pix] at (c>>4)*272 + (c&15)*16 + pix
  __shared__ __align__(16) float sQ[2][4][1088];   // 34.8KB
  __shared__ u16 sP[4 * 320];                      // per-wave attn (2.5KB)

  const int tid  = threadIdx.x;
  const int wv   = tid >> 6, lane = tid & 63;
  const int n = lane & 15, g = lane >> 4, rp = n >> 2, wl = n & 3;

  // ---- gamma/beta in registers (indexed by out-channel 16mt+n) ----
  float gwr[4], gbr[4];
#pragma unroll
  for (int mt = 0; mt < 4; ++mt) {
    gwr[mt] = gw[16 * mt + n];
    gbr[mt] = gb[16 * mt + n];
  }

  // ---- persistent weight fragments ----
  s16x8 Wq8[4][2], Wk8[4][2], Wv8[4][2];
  s16x4 Wf4[4][4];
#pragma unroll
  for (int a = 0; a < 4; ++a) {
#pragma unroll
    for (int c2 = 0; c2 < 2; ++c2) {
      Wq8[a][c2] = *(const s16x8*)(g_wpack + 0 * 4096 + ((a * 2 + c2) * 64 + lane) * 8);
      Wk8[a][c2] = *(const s16x8*)(g_wpack + 1 * 4096 + ((a * 2 + c2) * 64 + lane) * 8);
      Wv8[a][c2] = *(const s16x8*)(g_wpack + 2 * 4096 + ((a * 2 + c2) * 64 + lane) * 8);
    }
#pragma unroll
    for (int c4 = 0; c4 < 4; ++c4)
      Wf4[a][c4] = *(const s16x4*)(g_wpack + 3 * 4096 + ((a * 4 + c4) * 64 + lane) * 4);
  }

  // per-lane source offsets (within this wave's block)
  // Xq stage instr i: lane -> channel 16i+(l>>2), row l&3 (full 16B row)
  const uint32_t vq = (uint32_t)(lane >> 2) * 65536u + (uint32_t)(lane & 3) * 256u;
  // Xr: lane -> pixel (rp, wl) of channels 32kt + 8g + j
  const uint32_t vr = (uint32_t)g * 524288u + (uint32_t)rp * 256u + (uint32_t)wl;

  float* qA = &sQ[0][wv][0];
  float* qB = &sQ[1][wv][0];
  u16*   sPw = &sP[wv * 320];

  // XCD-contiguous swizzle over 1024 = 8 * 128 WGs; 8 strips per WG
  const int bid = blockIdx.x;
  const int wid = (bid & 7) * 128 + (bid >> 3);
  const int si0 = wid * 8;

  auto sbase = [](int si) -> uint32_t {
    return ((uint32_t)si >> 10) * 4194304u + (((uint32_t)si >> 4) & 63) * 1024u +
           ((uint32_t)si & 15) * 16u;
  };
  const uint32_t wv4 = (uint32_t)wv * 4u;   // block column within strip

  // ---- prologue: block-0 Xq staging, full drain ----
  uint32_t bb = sbase(si0) + wv4;
#pragma unroll
  for (int i = 0; i < 4; ++i)
    gload_lds16(qx + bb + vq + (uint32_t)i * 1048576u, &qA[i * 272]);
  asm volatile("s_waitcnt vmcnt(0)" ::: "memory");

  const f32x4 zero = {0.f, 0.f, 0.f, 0.f};

#pragma unroll 1
  for (int t = 0; t < 8; ++t) {
    const uint32_t nbb = sbase(si0 + (t < 7 ? t + 1 : t)) + wv4;
    float* qc = (t & 1) ? qB : qA;
    float* qn = (t & 1) ? qA : qB;

    // gate: Xq(t) staged (stores(t-1) are the <=4 youngest VMEM)
    asm volatile("s_waitcnt vmcnt(4)" ::: "memory");
    __builtin_amdgcn_sched_barrier(0);

    // ---- issue Xr(t) per-lane loads ----
    float xr[2][8];
#pragma unroll
    for (int kt = 0; kt < 2; ++kt)
#pragma unroll
      for (int j = 0; j < 8; ++j)
        xr[kt][j] = rx[bb + vr + (uint32_t)(32 * kt + j) * 65536u];
    __builtin_amdgcn_sched_barrier(0);

    // ---- issue Xq(t+1) staging into the other buffer ----
    if (t < 7) {
#pragma unroll
      for (int i = 0; i < 4; ++i)
        gload_lds16(qx + nbb + vq + (uint32_t)i * 1048576u, &qn[i * 272]);
    }
    __builtin_amdgcn_sched_barrier(0);

    // ---- Xq extract (2-way banks, free) + q projection ----
    s16x8 fqh[2], fql[2];
#pragma unroll
    for (int kt = 0; kt < 2; ++kt)
#pragma unroll
      for (int j = 0; j < 8; ++j) {
        const int c = 32 * kt + 8 * g + j;
        float x1 = qc[(c >> 4) * 272 + (c & 15) * 16 + n];
        bf16 h = (bf16)x1;
        fqh[kt][j] = (short)__builtin_bit_cast(u16, h);
        fql[kt][j] = (short)bfbits(x1 - (float)h);
      }
    f32x4 aq[4];
#pragma unroll
    for (int mt = 0; mt < 4; ++mt) {
      aq[mt] = zero;
#pragma unroll
      for (int kt = 0; kt < 2; ++kt) {
        aq[mt] = MFMA32(Wq8[mt][kt], fqh[kt], aq[mt]);
        aq[mt] = MFMA32(Wq8[mt][kt], fql[kt], aq[mt]);
      }
    }

    // ---- Xr cvt + k,v projections ----
    s16x8 frh[2], frl[2];
#pragma unroll
    for (int kt = 0; kt < 2; ++kt)
#pragma unroll
      for (int j = 0; j < 8; ++j) {
        float x2 = xr[kt][j];
        bf16 h = (bf16)x2;
        frh[kt][j] = (short)__builtin_bit_cast(u16, h);
        frl[kt][j] = (short)bfbits(x2 - (float)h);
      }
    f32x4 ak[4], av[4];
#pragma unroll
    for (int mt = 0; mt < 4; ++mt) { ak[mt] = zero; av[mt] = zero; }
#pragma unroll
    for (int mt = 0; mt < 4; ++mt)
#pragma unroll
      for (int kt = 0; kt < 2; ++kt) {
        ak[mt] = MFMA32(Wk8[mt][kt], frh[kt], ak[mt]);
        ak[mt] = MFMA32(Wk8[mt][kt], frl[kt], ak[mt]);
      }
#pragma unroll
    for (int nt2 = 0; nt2 < 4; ++nt2)
#pragma unroll
      for (int kt = 0; kt < 2; ++kt)
        av[nt2] = MFMA32(frh[kt], Wv8[nt2][kt], av[nt2]);

    // ---- split q,k accumulators (energy frags, same lane) ----
    s16x4 qh[4], ql[4], kh[4], kl[4];
#pragma unroll
    for (int kt = 0; kt < 4; ++kt)
#pragma unroll
      for (int r = 0; r < 4; ++r) {
        bf16 h = (bf16)aq[kt][r];
        qh[kt][r] = (short)__builtin_bit_cast(u16, h);
        ql[kt][r] = (short)bfbits(aq[kt][r] - (float)h);
        bf16 h2 = (bf16)ak[kt][r];
        kh[kt][r] = (short)__builtin_bit_cast(u16, h2);
        kl[kt][r] = (short)bfbits(ak[kt][r] - (float)h2);
      }

    // ---- energy = q^T k : 3 independent chains ----
    f32x4 e0 = zero, e1 = zero, e2 = zero;
#pragma unroll
    for (int kt = 0; kt < 4; ++kt) {
      e0 = MFMA16(qh[kt], kh[kt], e0);
      e1 = MFMA16(qh[kt], kl[kt], e1);
      e2 = MFMA16(ql[kt], kh[kt], e2);
    }

    // ---- softmax over refpix (DPP row butterflies) ----
#pragma unroll
    for (int r = 0; r < 4; ++r) {
      float x = (e0[r] + e1[r]) + e2[r];
      float m = x;
      m = fmaxf(m, DPP_ROR(m, 8));
      m = fmaxf(m, DPP_ROR(m, 4));
      m = fmaxf(m, DPP_ROR(m, 2));
      m = fmaxf(m, DPP_ROR(m, 1));
      float p = __expf(x - m);
      float s = p;
      s += DPP_ROR(s, 8);
      s += DPP_ROR(s, 4);
      s += DPP_ROR(s, 2);
      s += DPP_ROR(s, 1);
      sPw[(4 * g + r) * 20 + n] = bfbits(p * __builtin_amdgcn_rcpf(s));
    }

    // ---- O tiles: A = v (same lane), B = attn^T (wave-private sP) ----
    s16x4 pa = *(const s16x4*)&sPw[n * 20 + 4 * g];
    f32x4 ao[4];
#pragma unroll
    for (int mt = 0; mt < 4; ++mt) {
      s16x4 vb;
#pragma unroll
      for (int j = 0; j < 4; ++j) vb[j] = (short)bfbits(av[mt][j]);
      ao[mt] = MFMA16(vb, pa, zero);   // ao[kt][r] = O[16kt+4g+r][n]
    }

    // ---- x^T = O^T * Wfc^T : A = ao as bf16 (same lane!), B = Wf4 ----
    // xaT[mt][r] = x[16mt+n][pixel 4g+r]  -> dense store layout
    s16x4 obA[4];
#pragma unroll
    for (int kt = 0; kt < 4; ++kt)
#pragma unroll
      for (int j = 0; j < 4; ++j) obA[kt][j] = (short)bfbits(ao[kt][j]);
    f32x4 xaT[4];
#pragma unroll
    for (int mt = 0; mt < 4; ++mt) {
      xaT[mt] = zero;
#pragma unroll
      for (int kt = 0; kt < 4; ++kt)
        xaT[mt] = MFMA16(obA[kt], Wf4[mt][kt], xaT[mt]);
    }

    // ---- GroupNorm over 64x16 ----
    float s1 = 0.f, s2 = 0.f;
#pragma unroll
    for (int mt = 0; mt < 4; ++mt)
#pragma unroll
      for (int r = 0; r < 4; ++r) {
        float v = xaT[mt][r];
        s1 += v; s2 += v * v;
      }
    s1 += DPP_ROR(s1, 8);  s2 += DPP_ROR(s2, 8);
    s1 += DPP_ROR(s1, 4);  s2 += DPP_ROR(s2, 4);
    s1 += DPP_ROR(s1, 2);  s2 += DPP_ROR(s2, 2);
    s1 += DPP_ROR(s1, 1);  s2 += DPP_ROR(s2, 1);
    s1 += __shfl_xor(s1, 16);  s2 += __shfl_xor(s2, 16);
    s1 += __shfl_xor(s1, 32);  s2 += __shfl_xor(s2, 32);
    const float mean = s1 * (1.f / 1024.f);
    const float var  = s2 * (1.f / 1024.f) - mean * mean;
    const float rstd = rsqrtf(var + 1e-5f);

    // ---- residual from staging buffer (b128) + affine + dense store ----
#pragma unroll
    for (int mt = 0; mt < 4; ++mt) {
      f4 q0 = *(const f4*)&qc[mt * 272 + n * 16 + 4 * g];  // X[16mt+n][4g..4g+3]
      f4 o;
#pragma unroll
      for (int r = 0; r < 4; ++r)
        o[r] = (xaT[mt][r] - mean) * rstd * gwr[mt] + gbr[mt] + q0[r];
      __builtin_nontemporal_store(
          o, (f4*)(out + bb + (uint32_t)(16 * mt + n) * 65536u + (uint32_t)g * 256u));
    }

    bb = nbb;
  }
}

extern "C" void kernel_launch(void* const* d_in, const int* in_sizes, int n_in,
                              void* d_out, int out_size, void* d_ws, size_t ws_size,
                              hipStream_t stream) {
  const float* qx  = (const float*)d_in[0];
  const float* rx  = (const float*)d_in[1];
  const float* Wq  = (const float*)d_in[2];
  const float* Wk  = (const float*)d_in[3];
  const float* Wv  = (const float*)d_in[4];
  const float* Wfc = (const float*)d_in[5];
  const float* gw  = (const float*)d_in[6];
  const float* gb  = (const float*)d_in[7];
  float* out = (float*)d_out;

  prep_w<<<dim3(32), dim3(64), 0, stream>>>(Wq, Wk, Wv, Wfc);
  // 1024 WGs x 4 barrier-free waves x 8 blocks; 16 waves/CU; LDS-pipe-lean
  cvbt18<<<dim3(1024), dim3(256), 0, stream>>>(qx, rx, gw, gb, out);
}

// Round 19
// 107.914 us; speedup vs baseline: 4.0261x; 4.0261x over previous
//
#include <hip/hip_runtime.h>
#include <cstdint>

// CrossViewBlockTransformer on MI355X (gfx950), round 19.
// RESTORE of R14 (108.26us, best) + parallelized prep_w (32 WGs, from R17).
// R14 = R10 structure (WG=256 strip-of-4, Xq gload_lds ping-pong w/ source
// XOR swizzle, per-lane Xr, 35.8KB LDS, counted vmcnt, register weights,
// same-lane MFMA chains) + DPP softmax/GN reductions + 3-chain energy.
// Cross-round evidence (R6=R10=R14 at 108-110us over wildly different
// structures; delivered BW pinned at ~3.5TB/s = per-CU HBM service rate for
// mixed read+write+gather): this decomposition is delivered-bandwidth-bound.
// Arithmetic identical to R14 (absmax 0.1484375).

typedef float  f4    __attribute__((ext_vector_type(4)));
typedef float  f32x4 __attribute__((ext_vector_type(4)));
typedef short  s16x4 __attribute__((ext_vector_type(4)));
typedef short  s16x8 __attribute__((ext_vector_type(8)));
typedef unsigned short u16;
typedef __bf16 bf16;

#define MFMA16(a,b,c) __builtin_amdgcn_mfma_f32_16x16x16bf16_1k((a),(b),(c),0,0,0)
#define MFMA32(a,b,c) __builtin_amdgcn_mfma_f32_16x16x32_bf16((a),(b),(c),0,0,0)

// DPP row_ror:N over 16-lane rows (VALU; row-aligned with our g-groups)
#define DPP_ROR(x, N)                                                         \
  __builtin_bit_cast(float, __builtin_amdgcn_mov_dpp(                         \
      __builtin_bit_cast(int, (x)), 0x120 + (N), 0xF, 0xF, 1))

// slot0=Wq(K32) slot1=Wk(K32) slot2=Wv(K32) slot3=Wfc(K16); 4 x 8KB
__device__ __align__(16) u16 g_wpack[4 * 4096];

__device__ __forceinline__ u16 bfbits(float x) {
  return __builtin_bit_cast(u16, (bf16)x);
}

__device__ __forceinline__ void gload_lds16(const float* g, float* l) {
  __builtin_amdgcn_global_load_lds(
      (const __attribute__((address_space(1))) void*)g,
      (__attribute__((address_space(3))) void*)l, 16, 0, 0);
}

// K32 frag: pack[t=a*2+b][l][j0..7] = W[16a + (l&15)][32b + 8*(l>>4) + j]
// K16 frag: pack[t=a*4+b][l][j0..3] = W[16a + (l&15)][16b + 4*(l>>4) + j]
__global__ void prep_w(const float* __restrict__ Wq, const float* __restrict__ Wk,
                       const float* __restrict__ Wv, const float* __restrict__ Wfc)
{
  const int t = blockIdx.x * 64 + threadIdx.x;   // 32 WGs x 64 = 2048 threads
  const float* Wm[3] = {Wq, Wk, Wv};
#pragma unroll
  for (int s = 0; s < 3; ++s) {
    const float* W = Wm[s];
    if (t < 512) {
      const int tile = t >> 6, l = t & 63;
      const int row = 16 * (tile >> 1) + (l & 15);
      const int col = 32 * (tile & 1) + 8 * (l >> 4);
#pragma unroll
      for (int j = 0; j < 8; ++j)
        g_wpack[s * 4096 + t * 8 + j] = bfbits(W[row * 64 + col + j]);
    }
  }
  if (t < 1024) {
    const int tile = t >> 6, l = t & 63;
    const int row = 16 * (tile >> 2) + (l & 15);
    const int col = 16 * (tile & 3) + 4 * (l >> 4);
#pragma unroll
    for (int j = 0; j < 4; ++j)
      g_wpack[3 * 4096 + t * 4 + j] = bfbits(Wfc[row * 64 + col + j]);
  }
}

__global__ void __launch_bounds__(256, 2)
cvbt19(const float* __restrict__ qx, const float* __restrict__ rx,
       const float* __restrict__ gw, const float* __restrict__ gb,
       float* __restrict__ out)
{
  // strip-slot layout: element (c, r, w4group, wl) at float index
  //   c*64 + r*16 + 4*(w4 ^ r ^ ((c>>3)&3)) + wl      (swizzle in source addr)
  __shared__ __align__(16) float sQ[2][4096];  // Xq ping-pong / out staging (2x16KB)
  __shared__ u16   sP[4 * 320];                // per-wave attn (2.5KB)
  __shared__ float sGn[128];                   // gamma|beta (0.5KB)  => 35.5KB total

  const int tid  = threadIdx.x;
  const int wv   = tid >> 6, lane = tid & 63;
  const int n = lane & 15, g = lane >> 4, rp = n >> 2, wl = n & 3;

  if (tid < 128) sGn[tid] = (tid < 64) ? gw[tid] : gb[tid - 64];

  // ---- persistent weight fragments (all register-resident) ----
  s16x8 Wq8[4][2], Wk8[4][2], Wv8[4][2];
  s16x4 Wf4[4][4];
#pragma unroll
  for (int a = 0; a < 4; ++a) {
#pragma unroll
    for (int c2 = 0; c2 < 2; ++c2) {
      Wq8[a][c2] = *(const s16x8*)(g_wpack + 0 * 4096 + ((a * 2 + c2) * 64 + lane) * 8);
      Wk8[a][c2] = *(const s16x8*)(g_wpack + 1 * 4096 + ((a * 2 + c2) * 64 + lane) * 8);
      Wv8[a][c2] = *(const s16x8*)(g_wpack + 2 * 4096 + ((a * 2 + c2) * 64 + lane) * 8);
    }
#pragma unroll
    for (int c4 = 0; c4 < 4; ++c4)
      Wf4[a][c4] = *(const s16x4*)(g_wpack + 3 * 4096 + ((a * 4 + c4) * 64 + lane) * 4);
  }

  // ---- Xq chunk addressing: chunk j = s*4 + wv covers channels 4j..4j+3 ----
  uint32_t goff[4]; int lbase[4];
#pragma unroll
  for (int s = 0; s < 4; ++s) {
    const int j = s * 4 + wv;
    const int c = 4 * j + (lane >> 4);
    const int r = (lane >> 2) & 3, y = lane & 3;
    const int w4 = y ^ r ^ ((c >> 3) & 3);
    goff[s]  = (uint32_t)c * 65536u + (uint32_t)r * 256u + (uint32_t)w4 * 4u;
    lbase[s] = j * 256;
  }

  // XCD-contiguous swizzle over 1024 = 8 * 128 WGs; 8 strips per WG
  const int bid = blockIdx.x;
  const int wid = (bid & 7) * 128 + (bid >> 3);
  const int si0 = wid * 8;

  auto sbase = [](int si) -> uint32_t {
    return ((uint32_t)si >> 10) * 4194304u + (((uint32_t)si >> 4) & 63) * 1024u +
           ((uint32_t)si & 15) * 16u;
  };

  // per-lane Xr offset within a strip (pixel rp, block wv, col wl)
  const uint32_t xro = (uint32_t)rp * 256u + (uint32_t)(4 * wv + wl);

  // ---- prologue: strip-0 Xq loads, full drain ----
  uint32_t sb = sbase(si0);
#pragma unroll
  for (int s = 0; s < 4; ++s) gload_lds16(qx + sb + goff[s], &sQ[0][lbase[s]]);
  asm volatile("s_waitcnt vmcnt(0) lgkmcnt(0)" ::: "memory");

  const f32x4 zero = {0.f, 0.f, 0.f, 0.f};
  u16* sPw = &sP[wv * 320];
  int pp = 0;

#pragma unroll 1
  for (int t = 0; t < 8; ++t) {
    const uint32_t nsb = sbase(si0 + (t < 7 ? t + 1 : t));

    // B1: Xq(t) staged everywhere (stores(t-1) are the <=4 youngest VMEM)
    asm volatile("s_waitcnt vmcnt(4)" ::: "memory");
    __builtin_amdgcn_s_barrier();
    __builtin_amdgcn_sched_barrier(0);

    // ---- issue Xr(t) per-lane global loads (consumed later; 16 dwords) ----
    float xr[2][8];
#pragma unroll
    for (int kt = 0; kt < 2; ++kt)
#pragma unroll
      for (int j = 0; j < 8; ++j)
        xr[kt][j] = rx[sb + xro + (uint32_t)(32 * kt + 8 * g + j) * 65536u];
    __builtin_amdgcn_sched_barrier(0);

    // ---- issue Xq(t+1) prefetch (youngest VMEM: survives Xr-consume waits) ----
    if (t < 7) {
#pragma unroll
      for (int s = 0; s < 4; ++s)
        gload_lds16(qx + nsb + goff[s], &sQ[pp ^ 1][lbase[s]]);
    }
    __builtin_amdgcn_sched_barrier(0);

    // ---- Xq extract from LDS (independent of Xr) + q projection ----
    s16x8 fqh[2], fql[2];
#pragma unroll
    for (int kt = 0; kt < 2; ++kt)
#pragma unroll
      for (int j = 0; j < 8; ++j) {
        const int addr = (32 * kt + 8 * g + j) * 64 + rp * 16 + 4 * (wv ^ rp ^ g) + wl;
        float x1 = sQ[pp][addr];
        bf16 h = (bf16)x1;
        fqh[kt][j] = (short)__builtin_bit_cast(u16, h);
        fql[kt][j] = (short)bfbits(x1 - (float)h);
      }
    f32x4 aq[4];
#pragma unroll
    for (int mt = 0; mt < 4; ++mt) {
      aq[mt] = zero;
#pragma unroll
      for (int kt = 0; kt < 2; ++kt) {
        aq[mt] = MFMA32(Wq8[mt][kt], fqh[kt], aq[mt]);
        aq[mt] = MFMA32(Wq8[mt][kt], fql[kt], aq[mt]);
      }
    }

    // ---- Xr cvt (hi/lo) + k,v projections ----
    s16x8 frh[2], frl[2];
#pragma unroll
    for (int kt = 0; kt < 2; ++kt)
#pragma unroll
      for (int j = 0; j < 8; ++j) {
        float x2 = xr[kt][j];
        bf16 h = (bf16)x2;
        frh[kt][j] = (short)__builtin_bit_cast(u16, h);
        frl[kt][j] = (short)bfbits(x2 - (float)h);
      }
    f32x4 ak[4], av[4];
#pragma unroll
    for (int mt = 0; mt < 4; ++mt) { ak[mt] = zero; av[mt] = zero; }
#pragma unroll
    for (int mt = 0; mt < 4; ++mt)
#pragma unroll
      for (int kt = 0; kt < 2; ++kt) {
        ak[mt] = MFMA32(Wk8[mt][kt], frh[kt], ak[mt]);
        ak[mt] = MFMA32(Wk8[mt][kt], frl[kt], ak[mt]);
      }
#pragma unroll
    for (int nt2 = 0; nt2 < 4; ++nt2)
#pragma unroll
      for (int kt = 0; kt < 2; ++kt)
        av[nt2] = MFMA32(frh[kt], Wv8[nt2][kt], av[nt2]);

    // ---- split q,k accumulators (energy frags, same lane) ----
    s16x4 qh[4], ql[4], kh[4], kl[4];
#pragma unroll
    for (int kt = 0; kt < 4; ++kt)
#pragma unroll
      for (int r = 0; r < 4; ++r) {
        bf16 h = (bf16)aq[kt][r];
        qh[kt][r] = (short)__builtin_bit_cast(u16, h);
        ql[kt][r] = (short)bfbits(aq[kt][r] - (float)h);
        bf16 h2 = (bf16)ak[kt][r];
        kh[kt][r] = (short)__builtin_bit_cast(u16, h2);
        kl[kt][r] = (short)bfbits(ak[kt][r] - (float)h2);
      }

    // ---- energy = q^T k : 3 independent chains (depth 12 -> 4) ----
    f32x4 e0 = zero, e1 = zero, e2 = zero;
#pragma unroll
    for (int kt = 0; kt < 4; ++kt) {
      e0 = MFMA16(qh[kt], kh[kt], e0);
      e1 = MFMA16(qh[kt], kl[kt], e1);
      e2 = MFMA16(ql[kt], kh[kt], e2);
    }
    f32x4 e;
#pragma unroll
    for (int r = 0; r < 4; ++r) e[r] = (e0[r] + e1[r]) + e2[r];

    // ---- softmax over refpix: DPP row_ror butterfly (16-lane rows) ----
#pragma unroll
    for (int r = 0; r < 4; ++r) {
      float x = e[r];
      float m = x;
      m = fmaxf(m, DPP_ROR(m, 8));
      m = fmaxf(m, DPP_ROR(m, 4));
      m = fmaxf(m, DPP_ROR(m, 2));
      m = fmaxf(m, DPP_ROR(m, 1));
      float p = __expf(x - m);
      float s = p;
      s += DPP_ROR(s, 8);
      s += DPP_ROR(s, 4);
      s += DPP_ROR(s, 2);
      s += DPP_ROR(s, 1);
      sPw[(4 * g + r) * 20 + n] = bfbits(p * __builtin_amdgcn_rcpf(s));
    }

    // ---- O tiles: A = v (same lane), B = attn^T ----
    s16x4 pa = *(const s16x4*)&sPw[n * 20 + 4 * g];
    f32x4 ao[4];
#pragma unroll
    for (int mt = 0; mt < 4; ++mt) {
      s16x4 vb;
#pragma unroll
      for (int j = 0; j < 4; ++j) vb[j] = (short)bfbits(av[mt][j]);
      ao[mt] = MFMA16(vb, pa, zero);
    }

    // ---- x = Wfc * O (K16) ----
    s16x4 ob[4];
#pragma unroll
    for (int kt = 0; kt < 4; ++kt)
#pragma unroll
      for (int j = 0; j < 4; ++j) ob[kt][j] = (short)bfbits(ao[kt][j]);
    f32x4 xa[4];
#pragma unroll
    for (int mt = 0; mt < 4; ++mt) {
      xa[mt] = zero;
#pragma unroll
      for (int kt = 0; kt < 4; ++kt)
        xa[mt] = MFMA16(Wf4[mt][kt], ob[kt], xa[mt]);
    }

    // ---- GroupNorm over 64x16: DPP within 16-lane rows, shfl across rows ----
    float s1 = 0.f, s2 = 0.f;
#pragma unroll
    for (int mt = 0; mt < 4; ++mt)
#pragma unroll
      for (int r = 0; r < 4; ++r) {
        float v = xa[mt][r];
        s1 += v; s2 += v * v;
      }
    s1 += DPP_ROR(s1, 8);  s2 += DPP_ROR(s2, 8);
    s1 += DPP_ROR(s1, 4);  s2 += DPP_ROR(s2, 4);
    s1 += DPP_ROR(s1, 2);  s2 += DPP_ROR(s2, 2);
    s1 += DPP_ROR(s1, 1);  s2 += DPP_ROR(s2, 1);
    s1 += __shfl_xor(s1, 16);  s2 += __shfl_xor(s2, 16);
    s1 += __shfl_xor(s1, 32);  s2 += __shfl_xor(s2, 32);
    const float mean = s1 * (1.f / 1024.f);
    const float var  = s2 * (1.f / 1024.f) - mean * mean;
    const float rstd = rsqrtf(var + 1e-5f);

    // ---- affine + exact residual: RMW own-column slots of sQ[pp] ----
#pragma unroll
    for (int mt = 0; mt < 4; ++mt)
#pragma unroll
      for (int r = 0; r < 4; ++r) {
        const int row = 16 * mt + 4 * g + r;
        const int addr = row * 64 + rp * 16 + 4 * (wv ^ rp ^ ((row >> 3) & 3)) + wl;
        sQ[pp][addr] = (xa[mt][r] - mean) * rstd * sGn[row] + sGn[64 + row] + sQ[pp][addr];
      }

    // B3: staging visible to all waves
    asm volatile("s_waitcnt lgkmcnt(0)" ::: "memory");
    __builtin_amdgcn_s_barrier();
    __builtin_amdgcn_sched_barrier(0);

    // ---- cooperative coalesced store (non-temporal) ----
#pragma unroll
    for (int s = 0; s < 4; ++s) {
      f4 o = *(const f4*)&sQ[pp][lbase[s] + lane * 4];
      __builtin_nontemporal_store(o, (f4*)(out + sb + goff[s]));
    }

    pp ^= 1;
    sb = nsb;
  }
}

extern "C" void kernel_launch(void* const* d_in, const int* in_sizes, int n_in,
                              void* d_out, int out_size, void* d_ws, size_t ws_size,
                              hipStream_t stream) {
  const float* qx  = (const float*)d_in[0];
  const float* rx  = (const float*)d_in[1];
  const float* Wq  = (const float*)d_in[2];
  const float* Wk  = (const float*)d_in[3];
  const float* Wv  = (const float*)d_in[4];
  const float* Wfc = (const float*)d_in[5];
  const float* gw  = (const float*)d_in[6];
  const float* gb  = (const float*)d_in[7];
  float* out = (float*)d_out;

  prep_w<<<dim3(32), dim3(64), 0, stream>>>(Wq, Wk, Wv, Wfc);
  // 1024 WGs x 8 strips (R14 grid; best measured config at 108.26us)
  cvbt19<<<dim3(1024), dim3(256), 0, stream>>>(qx, rx, gw, gb, out);
}